// Round 1
// baseline (95.610 us; speedup 1.0000x reference)
//
#include <hip/hip_runtime.h>

// LSTM cell, B=4096, D=H=1024. Strategy:
//   X = [inputs | h_prev]  (4096 x 2048) bf16   (ws, 16 MB)
//   Wct[g][h][k] = concat(W_g, U_g)^T bf16      (ws, 16 MB)  g in {f,i,c,o}
//   One fused GEMM: each block computes a 128(b) x 64(h) tile for ALL 4 gates,
//   epilogue applies sigmoid/tanh + c/h update, writes h_next and c_next.

typedef __attribute__((ext_vector_type(8))) short bfrag8;   // 8 bf16 (4 VGPRs)
typedef __attribute__((ext_vector_type(4))) float f32x4;    // MFMA accumulator

__device__ __forceinline__ unsigned int f2bf(float f) {
  unsigned int u = __builtin_bit_cast(unsigned int, f);
  // round-to-nearest-even bf16
  unsigned int r = (u + 0x7fffu + ((u >> 16) & 1u)) >> 16;
  return r & 0xffffu;
}

// ---------------- prep X: [inputs | h_prev] -> bf16 (4096 x 2048) -------------
__global__ __launch_bounds__(256) void prep_x(const float* __restrict__ inputs,
                                              const float* __restrict__ h_prev,
                                              unsigned short* __restrict__ X) {
  int idx = blockIdx.x * 256 + threadIdx.x;     // 0 .. 1M-1, 8 elems each
  int b  = idx >> 8;
  int k8 = (idx & 255) * 8;
  const float* src = (k8 < 1024) ? (inputs + (size_t)b * 1024 + k8)
                                 : (h_prev + (size_t)b * 1024 + (k8 - 1024));
  float4 v0 = ((const float4*)src)[0];
  float4 v1 = ((const float4*)src)[1];
  uint4 o;
  o.x = f2bf(v0.x) | (f2bf(v0.y) << 16);
  o.y = f2bf(v0.z) | (f2bf(v0.w) << 16);
  o.z = f2bf(v1.x) | (f2bf(v1.y) << 16);
  o.w = f2bf(v1.z) | (f2bf(v1.w) << 16);
  *(uint4*)(X + (size_t)b * 2048 + k8) = o;
}

// ------------- prep W: transpose+cast 8x (1024x1024 f32) -> Wct[g][h][k] -----
__global__ __launch_bounds__(256) void prep_w(
    const float* __restrict__ s0, const float* __restrict__ s1,
    const float* __restrict__ s2, const float* __restrict__ s3,
    const float* __restrict__ s4, const float* __restrict__ s5,
    const float* __restrict__ s6, const float* __restrict__ s7,
    unsigned short* __restrict__ Wct) {
  int blk = blockIdx.x;                 // 0..2047: 8 matrices x 256 tiles
  int m = blk >> 8;                     // matrix id: (W_f,U_f,W_i,U_i,W_c,U_c,W_o,U_o)
  const float* src = (m == 0) ? s0 : (m == 1) ? s1 : (m == 2) ? s2 : (m == 3) ? s3
                   : (m == 4) ? s4 : (m == 5) ? s5 : (m == 6) ? s6 : s7;
  int g = m >> 1, half = m & 1;
  unsigned short* dst = Wct + (size_t)g * 1024 * 2048 + (size_t)half * 1024;
  int t = blk & 255;
  int k0 = (t >> 4) * 64;               // source row block (k)
  int h0 = (t & 15) * 64;               // source col block (h)
  __shared__ float lt[64][68];          // 64x64 tile, padded stride (68*4 B = 16B mult)
  int tid = threadIdx.x;
  #pragma unroll
  for (int it = 0; it < 4; ++it) {
    int r  = (tid >> 4) + it * 16;      // k within tile
    int c4 = (tid & 15) * 4;            // h within tile
    float4 v = *(const float4*)(src + (size_t)(k0 + r) * 1024 + h0 + c4);
    lt[r][c4 + 0] = v.x; lt[r][c4 + 1] = v.y; lt[r][c4 + 2] = v.z; lt[r][c4 + 3] = v.w;
  }
  __syncthreads();
  #pragma unroll
  for (int it = 0; it < 4; ++it) {
    int hh  = (tid >> 4) + it * 16;     // h within tile (output row)
    int kk4 = (tid & 15) * 4;           // k within tile (output col)
    uint2 o;
    o.x = f2bf(lt[kk4 + 0][hh]) | (f2bf(lt[kk4 + 1][hh]) << 16);
    o.y = f2bf(lt[kk4 + 2][hh]) | (f2bf(lt[kk4 + 3][hh]) << 16);
    *(uint2*)(dst + (size_t)(h0 + hh) * 2048 + k0 + kk4) = o;
  }
}

// ---------------- fused 4-gate GEMM + LSTM epilogue --------------------------
// Block: 256 threads (4 waves, 2M x 2N). Tile: BM=128 rows x 64 h-cols x 4 gates.
// K = 2048, BK = 64. LDS: A[128][64] + B[4][64][64] bf16 = 48 KB, XOR-swizzled
// (slot ^= row&7 on 16B slots) so fragment ds_read_b128 is bank-conflict-free.
__global__ __launch_bounds__(256, 2) void lstm_gemm(
    const unsigned short* __restrict__ X, const unsigned short* __restrict__ Wct,
    const float* __restrict__ c_prev,
    const float* __restrict__ bfv, const float* __restrict__ biv,
    const float* __restrict__ bcv, const float* __restrict__ bov,
    float* __restrict__ out) {
  __shared__ __align__(16) char smem[49152];
  const int tid = threadIdx.x;
  const int lane = tid & 63, wid = tid >> 6;
  const int u = lane & 15, q = lane >> 4;
  const int wave_m = wid >> 1, wave_n = wid & 1;
  const int h0 = blockIdx.x * 64;       // 16 col-blocks
  const int row0 = blockIdx.y * 128;    // 32 row-blocks

  f32x4 acc[4][4][2];
  #pragma unroll
  for (int g = 0; g < 4; ++g)
    #pragma unroll
    for (int mi = 0; mi < 4; ++mi)
      #pragma unroll
      for (int ni = 0; ni < 2; ++ni)
        acc[g][mi][ni] = (f32x4){0.f, 0.f, 0.f, 0.f};

  #pragma unroll 1
  for (int kt = 0; kt < 32; ++kt) {
    const int kb = kt * 64;
    __syncthreads();
    // stage A: 128 rows x 64 k (1024 x 16B chunks, 4 per thread)
    #pragma unroll
    for (int i = 0; i < 4; ++i) {
      int c = tid + 256 * i;
      int row = c >> 3, slot = c & 7;
      int sw = slot ^ (row & 7);
      uint4 v = *(const uint4*)(X + (size_t)(row0 + row) * 2048 + kb + slot * 8);
      *(uint4*)(smem + row * 128 + sw * 16) = v;
    }
    // stage B: 4 gates x 64 h x 64 k (2048 chunks, 8 per thread)
    #pragma unroll
    for (int i = 0; i < 8; ++i) {
      int c = tid + 256 * i;
      int g = c >> 9, hr = (c >> 3) & 63, slot = c & 7;
      int sw = slot ^ (hr & 7);
      uint4 v = *(const uint4*)(Wct + (size_t)((g << 10) + h0 + hr) * 2048 + kb + slot * 8);
      *(uint4*)(smem + 16384 + g * 8192 + hr * 128 + sw * 16) = v;
    }
    __syncthreads();
    #pragma unroll
    for (int kk = 0; kk < 2; ++kk) {
      bfrag8 afr[4];
      #pragma unroll
      for (int mi = 0; mi < 4; ++mi) {
        int row = wave_m * 64 + mi * 16 + u;
        int sl = (kk * 4 + q) ^ (row & 7);
        afr[mi] = *(const bfrag8*)(smem + row * 128 + sl * 16);
      }
      #pragma unroll
      for (int g = 0; g < 4; ++g) {
        #pragma unroll
        for (int ni = 0; ni < 2; ++ni) {
          int hr = wave_n * 32 + ni * 16 + u;
          int sl = (kk * 4 + q) ^ (hr & 7);
          bfrag8 bfr = *(const bfrag8*)(smem + 16384 + g * 8192 + hr * 128 + sl * 16);
          #pragma unroll
          for (int mi = 0; mi < 4; ++mi)
            acc[g][mi][ni] = __builtin_amdgcn_mfma_f32_16x16x32_bf16(
                afr[mi], bfr, acc[g][mi][ni], 0, 0, 0);
        }
      }
    }
  }

  // epilogue: gates -> c_next, h_next.  C/D layout: col=lane&15, row=q*4+reg.
  #pragma unroll
  for (int ni = 0; ni < 2; ++ni) {
    int h = h0 + wave_n * 32 + ni * 16 + u;
    float Bf = bfv[h], Bi = biv[h], Bc = bcv[h], Bo = bov[h];
    #pragma unroll
    for (int mi = 0; mi < 4; ++mi) {
      #pragma unroll
      for (int j = 0; j < 4; ++j) {
        int b = row0 + wave_m * 64 + mi * 16 + q * 4 + j;
        float pf = acc[0][mi][ni][j] + Bf;
        float pi = acc[1][mi][ni][j] + Bi;
        float pc = acc[2][mi][ni][j] + Bc;
        float po = acc[3][mi][ni][j] + Bo;
        float fg = 1.f / (1.f + __expf(-pf));
        float ig = 1.f / (1.f + __expf(-pi));
        float ct = 2.f / (1.f + __expf(-2.f * pc)) - 1.f;
        float og = 1.f / (1.f + __expf(-po));
        float cn = fg * c_prev[(size_t)b * 1024 + h] + ig * ct;
        float hn = og * (2.f / (1.f + __expf(-2.f * cn)) - 1.f);
        out[(size_t)b * 1024 + h] = hn;                      // h_next
        out[(size_t)4096 * 1024 + (size_t)b * 1024 + h] = cn; // c_next
      }
    }
  }
}

extern "C" void kernel_launch(void* const* d_in, const int* in_sizes, int n_in,
                              void* d_out, int out_size, void* d_ws, size_t ws_size,
                              hipStream_t stream) {
  const float* inputs = (const float*)d_in[0];
  const float* h_prev = (const float*)d_in[1];
  const float* c_prev = (const float*)d_in[2];
  const float* Wf = (const float*)d_in[3];
  const float* Uf = (const float*)d_in[4];
  const float* bf = (const float*)d_in[5];
  const float* Wi = (const float*)d_in[6];
  const float* Ui = (const float*)d_in[7];
  const float* bi = (const float*)d_in[8];
  const float* Wc = (const float*)d_in[9];
  const float* Uc = (const float*)d_in[10];
  const float* bc = (const float*)d_in[11];
  const float* Wo = (const float*)d_in[12];
  const float* Uo = (const float*)d_in[13];
  const float* bo = (const float*)d_in[14];
  float* out = (float*)d_out;

  unsigned short* X   = (unsigned short*)d_ws;                 // 4096x2048 bf16, 16 MB
  unsigned short* Wct = X + (size_t)4096 * 2048;               // 4x1024x2048 bf16, 16 MB

  prep_x<<<4096, 256, 0, stream>>>(inputs, h_prev, X);
  prep_w<<<2048, 256, 0, stream>>>(Wf, Uf, Wi, Ui, Wc, Uc, Wo, Uo, Wct);
  dim3 grid(16, 32);
  lstm_gemm<<<grid, 256, 0, stream>>>(X, Wct, c_prev, bf, bi, bc, bo, out);
}

// Round 2
// 88.729 us; speedup vs baseline: 1.0775x; 1.0775x over previous
//
#include <hip/hip_runtime.h>

// LSTM cell, B=4096, D=H=1024.
//   X = [inputs | h_prev]  (4096 x 2048) bf16   (ws, 16 MB)
//   Wct[g][h][k] = concat(W_g,U_g)^T bf16       (ws, 16 MB)
//   8-phase 256x256 fused GEMM (4 gates x 64 h per block) + LSTM epilogue.

typedef __attribute__((ext_vector_type(8))) short bfrag8;   // 8 bf16 (4 VGPRs)
typedef __attribute__((ext_vector_type(4))) float f32x4;    // MFMA accumulator

__device__ __forceinline__ unsigned int f2bf(float f) {
  unsigned int u = __builtin_bit_cast(unsigned int, f);
  unsigned int r = (u + 0x7fffu + ((u >> 16) & 1u)) >> 16;
  return r & 0xffffu;
}

// ---------------- prep X: [inputs | h_prev] -> bf16 (4096 x 2048) ------------
__global__ __launch_bounds__(256) void prep_x(const float* __restrict__ inputs,
                                              const float* __restrict__ h_prev,
                                              unsigned short* __restrict__ X) {
  int idx = blockIdx.x * 256 + threadIdx.x;
  int b  = idx >> 8;
  int k8 = (idx & 255) * 8;
  const float* src = (k8 < 1024) ? (inputs + (size_t)b * 1024 + k8)
                                 : (h_prev + (size_t)b * 1024 + (k8 - 1024));
  float4 v0 = ((const float4*)src)[0];
  float4 v1 = ((const float4*)src)[1];
  uint4 o;
  o.x = f2bf(v0.x) | (f2bf(v0.y) << 16);
  o.y = f2bf(v0.z) | (f2bf(v0.w) << 16);
  o.z = f2bf(v1.x) | (f2bf(v1.y) << 16);
  o.w = f2bf(v1.z) | (f2bf(v1.w) << 16);
  *(uint4*)(X + (size_t)b * 2048 + k8) = o;
}

// ------------- prep W: transpose+cast 8x (1024x1024 f32) -> Wct[g][h][k] -----
__global__ __launch_bounds__(256) void prep_w(
    const float* __restrict__ s0, const float* __restrict__ s1,
    const float* __restrict__ s2, const float* __restrict__ s3,
    const float* __restrict__ s4, const float* __restrict__ s5,
    const float* __restrict__ s6, const float* __restrict__ s7,
    unsigned short* __restrict__ Wct) {
  int blk = blockIdx.x;
  int m = blk >> 8;
  const float* src = (m == 0) ? s0 : (m == 1) ? s1 : (m == 2) ? s2 : (m == 3) ? s3
                   : (m == 4) ? s4 : (m == 5) ? s5 : (m == 6) ? s6 : s7;
  int g = m >> 1, half = m & 1;
  unsigned short* dst = Wct + (size_t)g * 1024 * 2048 + (size_t)half * 1024;
  int t = blk & 255;
  int k0 = (t >> 4) * 64;
  int h0 = (t & 15) * 64;
  __shared__ float lt[64][68];
  int tid = threadIdx.x;
  #pragma unroll
  for (int it = 0; it < 4; ++it) {
    int r  = (tid >> 4) + it * 16;
    int c4 = (tid & 15) * 4;
    float4 v = *(const float4*)(src + (size_t)(k0 + r) * 1024 + h0 + c4);
    lt[r][c4 + 0] = v.x; lt[r][c4 + 1] = v.y; lt[r][c4 + 2] = v.z; lt[r][c4 + 3] = v.w;
  }
  __syncthreads();
  #pragma unroll
  for (int it = 0; it < 4; ++it) {
    int hh  = (tid >> 4) + it * 16;
    int kk4 = (tid & 15) * 4;
    uint2 o;
    o.x = f2bf(lt[kk4 + 0][hh]) | (f2bf(lt[kk4 + 1][hh]) << 16);
    o.y = f2bf(lt[kk4 + 2][hh]) | (f2bf(lt[kk4 + 3][hh]) << 16);
    *(uint2*)(dst + (size_t)(h0 + hh) * 2048 + k0 + kk4) = o;
  }
}

// ---------------- 8-phase fused 4-gate GEMM + LSTM epilogue ------------------
// 512 thr, 8 waves (2M x 4N). BM=256 rows, N-tile = 256 cols = 4 gates x 64 h,
// col c -> (wn=c>>6, gate=(c>>4)&3, h = h0 + wn*16 + (c&15)). BK=64, K=2048 ->
// 32 K-tiles, 2 per iteration, 8 phases each. 128 KiB LDS:
//   A half0: buf0 @0,     buf1 @16384   (rows   0-127 x 64k)
//   A half1: buf0 @32768, buf1 @49152   (rows 128-255)
//   B half0: buf0 @65536, buf1 @81920   (cols   0-127)
//   B half1: buf0 @98304, buf1 @114688  (cols 128-255)
// global_load_lds width 16, linear dest, pre-swizzled source (slot^=(row&7)),
// ds_read applies the same XOR -> conflict-free.

#define FENCE() asm volatile("" ::: "memory")
#define BARRIER() do { FENCE(); __builtin_amdgcn_s_barrier(); FENCE(); } while (0)
#define VMCNT(n) asm volatile("s_waitcnt vmcnt(" #n ")" ::: "memory")
#define LGKM0_SCHED() do { asm volatile("s_waitcnt lgkmcnt(0)" ::: "memory"); \
                           __builtin_amdgcn_sched_barrier(0); } while (0)
#define GLOAD16(gp, lp) __builtin_amdgcn_global_load_lds( \
    (const __attribute__((address_space(1))) unsigned int*)(gp), \
    (__attribute__((address_space(3))) unsigned int*)(lp), 16, 0, 0)
#define DSR(dst, addr, off) asm volatile("ds_read_b128 %0, %1 offset:%c2" \
    : "=v"(dst) : "v"(addr), "n"(off))

#define READ_A8(arr, BUF, RB) do { \
  DSR(arr[0], aA0, (BUF)*16384 + (RB)*128 + 0);    \
  DSR(arr[1], aA1, (BUF)*16384 + (RB)*128 + 0);    \
  DSR(arr[2], aA0, (BUF)*16384 + (RB)*128 + 2048); \
  DSR(arr[3], aA1, (BUF)*16384 + (RB)*128 + 2048); \
  DSR(arr[4], aA0, (BUF)*16384 + (RB)*128 + 4096); \
  DSR(arr[5], aA1, (BUF)*16384 + (RB)*128 + 4096); \
  DSR(arr[6], aA0, (BUF)*16384 + (RB)*128 + 6144); \
  DSR(arr[7], aA1, (BUF)*16384 + (RB)*128 + 6144); \
} while (0)

#define READ_B4(arr, BUF, CB) do { \
  DSR(arr[0], aB0, (BUF)*16384 + (CB)*128 + 0);    \
  DSR(arr[1], aB1, (BUF)*16384 + (CB)*128 + 0);    \
  DSR(arr[2], aB0, (BUF)*16384 + (CB)*128 + 2048); \
  DSR(arr[3], aB1, (BUF)*16384 + (CB)*128 + 2048); \
} while (0)

#define STAGE_A(BUF, H, kt) do { int _kb = ((kt) < 32 ? (kt) : 31) * 64; \
  GLOAD16(pA0 + (size_t)(H) * 262144 + _kb, smem + (H)*32768 + (BUF)*16384 + stbase); \
  GLOAD16(pA1 + (size_t)(H) * 262144 + _kb, smem + (H)*32768 + (BUF)*16384 + stbase + 1024); \
} while (0)

#define STAGE_B0(BUF, kt) do { int _kb = ((kt) < 32 ? (kt) : 31) * 64; \
  GLOAD16(pB00 + _kb, smem + 65536 + (BUF)*16384 + stbase); \
  GLOAD16(pB01 + _kb, smem + 65536 + (BUF)*16384 + stbase + 1024); \
} while (0)

#define STAGE_B1(BUF, kt) do { int _kb = ((kt) < 32 ? (kt) : 31) * 64; \
  GLOAD16(pB10 + _kb, smem + 98304 + (BUF)*16384 + stbase); \
  GLOAD16(pB11 + _kb, smem + 98304 + (BUF)*16384 + stbase + 1024); \
} while (0)

#define MFMA16(B4, G0, M0) do { \
  __builtin_amdgcn_s_setprio(1); \
  _Pragma("unroll") for (int ni = 0; ni < 2; ++ni) \
  _Pragma("unroll") for (int mi = 0; mi < 4; ++mi) \
  _Pragma("unroll") for (int kk = 0; kk < 2; ++kk) \
    acc[(G0)+ni][(M0)+mi] = __builtin_amdgcn_mfma_f32_16x16x32_bf16( \
        a[mi*2+kk], (B4)[ni*2+kk], acc[(G0)+ni][(M0)+mi], 0, 0, 0); \
  __builtin_amdgcn_s_setprio(0); \
} while (0)

__global__ __launch_bounds__(512, 2) void lstm_gemm(
    const unsigned short* __restrict__ X, const unsigned short* __restrict__ Wct,
    const float* __restrict__ c_prev,
    const float* __restrict__ bfv, const float* __restrict__ biv,
    const float* __restrict__ bcv, const float* __restrict__ bov,
    float* __restrict__ out) {
  extern __shared__ __align__(16) char smem[];
  const int tid = threadIdx.x;
  const int lane = tid & 63, w = tid >> 6;
  const int u = lane & 15, q = (lane >> 4) & 3;
  const int wm = w >> 2, wn = w & 3;

  // bijective XCD swizzle (256 % 8 == 0): 2 row-panels per XCD
  const int bid = blockIdx.x;
  const int swz = (bid & 7) * 32 + (bid >> 3);
  const int h0 = (swz & 15) * 64;
  const int row0 = (swz >> 4) * 256;

  const unsigned lds0 = (unsigned)(size_t)((__attribute__((address_space(3))) char*)smem);

  // fragment read addresses (XOR swizzle folded; row&7 == u&7 everywhere)
  const int sw0 = (q ^ (u & 7)) << 4;
  const int sw1 = ((q + 4) ^ (u & 7)) << 4;
  const unsigned aA0 = lds0 + wm * 32768 + u * 128 + sw0;
  const unsigned aA1 = lds0 + wm * 32768 + u * 128 + sw1;
  const unsigned aB0 = lds0 + 65536 + (wn >> 1) * 32768 + ((wn & 1) * 64 + u) * 128 + sw0;
  const unsigned aB1 = lds0 + 65536 + (wn >> 1) * 32768 + ((wn & 1) * 64 + u) * 128 + sw1;

  // staging: wave w loads chunks [w*128, w*128+128), 2 gload16 per half.
  const int stbase = w * 2048 + lane * 16;
  const int rA0 = w * 16 + (lane >> 3), rA1 = rA0 + 8;
  const int ssA = (lane & 7) ^ (rA0 & 7);           // source slot (pre-swizzle)
  const unsigned short* pA0 = X + (size_t)(row0 + rA0) * 2048 + ssA * 8;
  const unsigned short* pA1 = X + (size_t)(row0 + rA1) * 2048 + ssA * 8;
  auto wrow = [&](int C) { return (((C >> 4) & 3) << 10) + h0 + ((C >> 6) << 4) + (C & 15); };
  const unsigned short* pB00 = Wct + (size_t)wrow(rA0) * 2048 + ssA * 8;
  const unsigned short* pB01 = Wct + (size_t)wrow(rA1) * 2048 + ssA * 8;
  const unsigned short* pB10 = Wct + (size_t)wrow(128 + rA0) * 2048 + ssA * 8;
  const unsigned short* pB11 = Wct + (size_t)wrow(128 + rA1) * 2048 + ssA * 8;

  f32x4 acc[4][8];
  #pragma unroll
  for (int g = 0; g < 4; ++g)
    #pragma unroll
    for (int m = 0; m < 8; ++m)
      acc[g][m] = (f32x4){0.f, 0.f, 0.f, 0.f};

  bfrag8 a[8], bh[4], bl0[4], bl1[4];

  // prologue: issue KT0.{B0,B1,A0,A1}, KT1.{B0,B1}; wait KT0 in; preload bl0
  STAGE_B0(0, 0); STAGE_B1(0, 0); STAGE_A(0, 0, 0); STAGE_A(0, 1, 0);
  STAGE_B0(1, 1); STAGE_B1(1, 1);
  VMCNT(4);
  BARRIER();
  READ_B4(bl0, 0, 0);

  #pragma unroll 1
  for (int t = 0; t < 16; ++t) {
    const int kt1 = 2 * t + 1, kt2 = 2 * t + 2, kt3 = 2 * t + 3;
    // PH1: q(lo,lo) of even KT
    READ_A8(a, 0, 0);
    STAGE_A(1, 0, kt1);
    BARRIER(); LGKM0_SCHED();
    MFMA16(bl0, 0, 0);
    BARRIER();
    // PH2: q(lo,hi)
    READ_B4(bh, 0, 32);
    STAGE_A(1, 1, kt1);
    BARRIER(); LGKM0_SCHED();
    MFMA16(bh, 2, 0);
    BARRIER();
    // PH3: q(hi,hi)
    READ_A8(a, 0, 64);
    STAGE_B0(0, kt2);
    VMCNT(8);
    BARRIER(); LGKM0_SCHED();
    MFMA16(bh, 2, 4);
    BARRIER();
    // PH4: q(hi,lo); prefetch odd-KT B-lo
    READ_B4(bl1, 1, 0);
    STAGE_B1(0, kt2);
    VMCNT(4);
    BARRIER(); LGKM0_SCHED();
    MFMA16(bl0, 0, 4);
    BARRIER();
    // PH5: q(lo,lo) of odd KT
    READ_A8(a, 1, 0);
    STAGE_A(0, 0, kt2);
    BARRIER(); LGKM0_SCHED();
    MFMA16(bl1, 0, 0);
    BARRIER();
    // PH6: q(lo,hi)
    READ_B4(bh, 1, 32);
    STAGE_A(0, 1, kt2);
    BARRIER(); LGKM0_SCHED();
    MFMA16(bh, 2, 0);
    BARRIER();
    // PH7: q(hi,hi)
    READ_A8(a, 1, 64);
    STAGE_B0(1, kt3);
    VMCNT(8);
    BARRIER(); LGKM0_SCHED();
    MFMA16(bh, 2, 4);
    BARRIER();
    // PH8: q(hi,lo); prefetch next even-KT B-lo
    READ_B4(bl0, 0, 0);
    STAGE_B1(1, kt3);
    VMCNT(4);
    BARRIER(); LGKM0_SCHED();
    MFMA16(bl1, 0, 4);
    BARRIER();
  }
  VMCNT(0);  // drain dangling prefetches before LDS dealloc

  // epilogue: gates -> c_next, h_next.  C/D: col=lane&15, row=q*4+j.
  const int hcol = h0 + wn * 16 + u;
  const float Bgf = bfv[hcol], Bgi = biv[hcol], Bgc = bcv[hcol], Bgo = bov[hcol];
  const int rbw = row0 + wm * 128;
  #pragma unroll
  for (int m = 0; m < 8; ++m) {
    #pragma unroll
    for (int j = 0; j < 4; ++j) {
      const int b = rbw + m * 16 + q * 4 + j;
      float pf = acc[0][m][j] + Bgf;
      float pi = acc[1][m][j] + Bgi;
      float pc = acc[2][m][j] + Bgc;
      float po = acc[3][m][j] + Bgo;
      float fg = 1.f / (1.f + __expf(-pf));
      float ig = 1.f / (1.f + __expf(-pi));
      float ct = 2.f / (1.f + __expf(-2.f * pc)) - 1.f;
      float og = 1.f / (1.f + __expf(-po));
      float cn = fg * c_prev[(size_t)b * 1024 + hcol] + ig * ct;
      float hn = og * (2.f / (1.f + __expf(-2.f * cn)) - 1.f);
      out[(size_t)b * 1024 + hcol] = hn;
      out[(size_t)4096 * 1024 + (size_t)b * 1024 + hcol] = cn;
    }
  }
}

extern "C" void kernel_launch(void* const* d_in, const int* in_sizes, int n_in,
                              void* d_out, int out_size, void* d_ws, size_t ws_size,
                              hipStream_t stream) {
  const float* inputs = (const float*)d_in[0];
  const float* h_prev = (const float*)d_in[1];
  const float* c_prev = (const float*)d_in[2];
  const float* Wf = (const float*)d_in[3];
  const float* Uf = (const float*)d_in[4];
  const float* bf = (const float*)d_in[5];
  const float* Wi = (const float*)d_in[6];
  const float* Ui = (const float*)d_in[7];
  const float* bi = (const float*)d_in[8];
  const float* Wc = (const float*)d_in[9];
  const float* Uc = (const float*)d_in[10];
  const float* bc = (const float*)d_in[11];
  const float* Wo = (const float*)d_in[12];
  const float* Uo = (const float*)d_in[13];
  const float* bo = (const float*)d_in[14];
  float* out = (float*)d_out;

  unsigned short* X   = (unsigned short*)d_ws;                 // 16 MB
  unsigned short* Wct = X + (size_t)4096 * 2048;               // 16 MB

  (void)hipFuncSetAttribute(reinterpret_cast<const void*>(lstm_gemm),
                            hipFuncAttributeMaxDynamicSharedMemorySize, 131072);

  prep_x<<<4096, 256, 0, stream>>>(inputs, h_prev, X);
  prep_w<<<2048, 256, 0, stream>>>(Wf, Uf, Wi, Ui, Wc, Uc, Wo, Uo, Wct);
  lstm_gemm<<<256, 512, 131072, stream>>>(X, Wct, c_prev, bf, bi, bc, bo, out);
}